// Round 11
// baseline (304.718 us; speedup 1.0000x reference)
//
#include <hip/hip_runtime.h>
#include <stdint.h>

// Problem constants: B=8, N=1024, IN_F=1024, E=256, H=4, A=64
typedef __attribute__((ext_vector_type(8))) short short8;
typedef __attribute__((ext_vector_type(4))) float f32x4;

// WhF16 frag-tile layout (k1 epilogue -> k2):
//   element (hb, e, m): et=e>>4, el=e&15, mt=m>>5, ml=m&31
//   u16 idx = ((hb*16+et)*32 + mt)*512 + (ml>>3)*128 + el*8 + (ml&7)
// WactF frag-tile layout (prep -> k3 part): element (k, col), k in [0,1024):
//   u16 idx = ((k>>5)*4 + (col>>4))*512 + (((k>>3)&3)*16 + (col&15))*8 + (k&7)

__device__ __forceinline__ float b2f(unsigned short u) {
    union { unsigned int i; float f; } v; v.i = ((unsigned int)u) << 16; return v.f;
}
__device__ __forceinline__ unsigned short f2b(float f) {
    union { float f; unsigned int i; } v; v.f = f;
    unsigned int u = v.i;
    u = (u + 0x7FFFu + ((u >> 16) & 1u)) >> 16;
    return (unsigned short)u;
}
__device__ __forceinline__ void glds16(const void* g, const void* l) {
    __builtin_amdgcn_global_load_lds(
        (const __attribute__((address_space(1))) unsigned int*)g,
        (__attribute__((address_space(3))) unsigned int*)l, 16, 0, 0);
}

__device__ __forceinline__ void cvt8(const void* in, unsigned short* out,
                                     int f, int grp) {
    if (f) {
        ((ushort4*)out)[grp * 2]     = ((const ushort4*)in)[grp * 2];
        ((ushort4*)out)[grp * 2 + 1] = ((const ushort4*)in)[grp * 2 + 1];
    } else {
        const float4* p = (const float4*)in + (size_t)grp * 2;
        float4 a = p[0], b = p[1];
        ushort4 o0, o1;
        o0.x = f2b(a.x); o0.y = f2b(a.y); o0.z = f2b(a.z); o0.w = f2b(a.w);
        o1.x = f2b(b.x); o1.y = f2b(b.y); o1.z = f2b(b.z); o1.w = f2b(b.w);
        ((ushort4*)out)[grp * 2]     = o0;
        ((ushort4*)out)[grp * 2 + 1] = o1;
    }
}

// prep_all: single launch replacing prep_small+conv8+t2_all+zero.
// Blocks: [0,4096) x-convert | [4096,4352) W transpose | [4352,4416) zero f1/f2
//         | 4416 smalls+flag | [4417,4433) WactF frag-tile transform.
// Each non-zero block re-derives the dtype flag from x[0:64] (256B, L2-hot).
__global__ __launch_bounds__(256) void prep_all(
        const unsigned int* __restrict__ x4,
        const void* __restrict__ x, const void* __restrict__ W,
        const void* __restrict__ Wact,
        const void* __restrict__ a1, const void* __restrict__ a2,
        const void* __restrict__ bact,
        unsigned short* __restrict__ xb, unsigned short* __restrict__ WT,
        unsigned short* __restrict__ WactF,
        unsigned short* __restrict__ a1b, unsigned short* __restrict__ a2b,
        unsigned short* __restrict__ bactb,
        int* __restrict__ flag, float4* __restrict__ fz) {
    __shared__ unsigned int tile[64 * 65];
    __shared__ int sflag;
    int tid = threadIdx.x;
    int bid = blockIdx.x;
    if (bid >= 4352 && bid < 4416) {                  // zero f1/f2 (256 KB)
        fz[(bid - 4352) * 256 + tid] = float4{0.f, 0.f, 0.f, 0.f};
        return;
    }
    if (tid < 64) {                                   // per-block dtype detect
        unsigned int wv = x4[tid];
        unsigned int e = (wv >> 7) & 0xFF;
        unsigned long long m = __ballot(e >= 100 && e <= 140);
        if (tid == 0) sflag = (__popcll(m) >= 48) ? 1 : 0;
    }
    __syncthreads();
    int f = sflag;

    if (bid < 4096) {                                 // x -> xb bf16
        cvt8(x, xb, f, bid * 256 + tid);
        return;
    }
    if (bid < 4352) {                                 // W[bt] 1024x256 -> WT[bt] 256x1024
        int lb = bid - 4096;
        int c0 = (lb & 3) * 64;
        int r0 = ((lb >> 2) & 15) * 64;
        int bt = lb >> 6;
        int rl = tid >> 2;
        int cc = (tid & 3) * 16;
        size_t ibase = ((size_t)bt * 1024 + (r0 + rl)) * 256 + c0 + cc;
        unsigned short v[16];
        if (f) {
            const unsigned short* p = (const unsigned short*)W + ibase;
            short8 a = *(const short8*)p;
            short8 b = *(const short8*)(p + 8);
#pragma unroll
            for (int j = 0; j < 8; j++) { v[j] = (unsigned short)a[j]; v[8 + j] = (unsigned short)b[j]; }
        } else {
            const float* p = (const float*)W + ibase;
#pragma unroll
            for (int j = 0; j < 16; j++) v[j] = f2b(p[j]);
        }
#pragma unroll
        for (int j = 0; j < 16; j++)
            tile[(cc + j) * 65 + rl] = v[j];
        __syncthreads();
        int cl = tid >> 2;
        int rch = (tid & 3) * 16;
        unsigned short o[16];
#pragma unroll
        for (int j = 0; j < 16; j++)
            o[j] = (unsigned short)tile[cl * 65 + rch + j];
        unsigned short* op = WT + ((size_t)bt * 256 + (c0 + cl)) * 1024 + r0 + rch;
#pragma unroll
        for (int q = 0; q < 4; q++) {
            ushort4 s; s.x = o[q*4]; s.y = o[q*4+1]; s.z = o[q*4+2]; s.w = o[q*4+3];
            ((ushort4*)op)[q] = s;
        }
        return;
    }
    if (bid == 4416) {                                // smalls + flag publish
        if (tid == 0) flag[0] = f;
        if (tid < 128) cvt8(a1, a1b, f, tid);
        else           cvt8(a2, a2b, f, tid - 128);
        if (tid < 8)   cvt8(bact, bactb, f, tid);
        return;
    }
    // WactF: blocks 4417..4432, each handles kt pair; Wact is [1024][64] row-major.
    {
        int lb = bid - 4417;                          // 0..15
#pragma unroll
        for (int ktt = 0; ktt < 2; ktt++) {
            int kt = lb * 2 + ktt;
            int kl = tid >> 3;                        // 0..31
            int cg = (tid & 7) * 8;                   // col group of 8
            int k = kt * 32 + kl;
            unsigned short v[8];
            if (f) {
                const unsigned short* p = (const unsigned short*)Wact + (size_t)k * 64 + cg;
                short8 a = *(const short8*)p;
#pragma unroll
                for (int j = 0; j < 8; j++) v[j] = (unsigned short)a[j];
            } else {
                const float* p = (const float*)Wact + (size_t)k * 64 + cg;
#pragma unroll
                for (int j = 0; j < 8; j++) v[j] = f2b(p[j]);
            }
#pragma unroll
            for (int q = 0; q < 8; q++) {
                int col = cg + q;
                size_t dst = ((size_t)(kt * 4 + (col >> 4)) * 512)
                             + (((kl >> 3) & 3) * 16 + (col & 15)) * 8 + (kl & 7);
                WactF[dst] = v[q];
            }
        }
    }
}

// Pack adj into TRANSPOSED bitmask maskT[b][mword=m>>5][n] (u32), via ballot.
__global__ void pack_adj(const int* __restrict__ adj,
                         unsigned int* __restrict__ maskT) {
    int gid = blockIdx.x * 256 + threadIdx.x;
    int lane = threadIdx.x & 63;
    unsigned long long m = __ballot(adj[gid] > 0);
    if (lane == 0) {
        int lin = gid >> 6;           // (b*1024+n)*16 + m0/64
        int mw = (lin & 15) * 2;
        int bn = lin >> 4;
        int b = bn >> 10, n = bn & 1023;
        maskT[(size_t)(b * 32 + mw) * 1024 + n]     = (unsigned int)m;
        maskT[(size_t)(b * 32 + mw + 1) * 1024 + n] = (unsigned int)(m >> 32);
    }
}

// K1: Wh = x @ W[h] -> WhF16 frag-tile bf16. Epilogue also accumulates
// f1 = Wh.a1, f2 = Wh.a2 (pre-scaled by log2e) via shfl-reduce + atomics.
__global__ __launch_bounds__(256) void k1_gemm(
        const unsigned short* __restrict__ x,
        const unsigned short* __restrict__ WT,      // [H][E=256][K=1024]
        unsigned short* __restrict__ WhF,
        const unsigned short* __restrict__ a1b,
        const unsigned short* __restrict__ a2b,
        float* __restrict__ f1, float* __restrict__ f2) {
    __shared__ unsigned short smA[8 * 512];
    __shared__ unsigned short smB[8 * 512];
    int tid = threadIdx.x;
    int w = tid >> 6, lane = tid & 63;
    int lr = lane & 15, lq = lane >> 4;
    int col0 = blockIdx.x * 128;
    int row0 = blockIdx.y * 128;
    int h = col0 >> 8;
    int e_base = col0 & 255;
    int b = row0 >> 10;
    int m_base = row0 & 1023;
    int wr = w >> 1, wc = w & 1;

    f32x4 acc[4][4] = {};

    for (int k0 = 0; k0 < 1024; k0 += 32) {
        __syncthreads();
#pragma unroll
        for (int s = 0; s < 2; s++) {
            int g = 2 * w + s;
            const unsigned short* srcA =
                x + (size_t)(row0 + g * 16 + lr) * 1024 + k0 + lq * 8;
            glds16(srcA, &smA[g * 512]);
            const unsigned short* srcB =
                WT + (size_t)(h * 256 + e_base + g * 16 + lr) * 1024 + k0 + lq * 8;
            glds16(srcB, &smB[g * 512]);
        }
        __syncthreads();
        short8 af[4], bf[4];
#pragma unroll
        for (int i = 0; i < 4; i++)
            af[i] = *(const short8*)&smA[(wr * 4 + i) * 512 + lane * 8];
#pragma unroll
        for (int j = 0; j < 4; j++)
            bf[j] = *(const short8*)&smB[(wc * 4 + j) * 512 + lane * 8];
#pragma unroll
        for (int i = 0; i < 4; i++)
#pragma unroll
            for (int j = 0; j < 4; j++)
                acc[i][j] = __builtin_amdgcn_mfma_f32_16x16x32_bf16(
                    af[i], bf[j], acc[i][j], 0, 0, 0);
    }

    // Epilogue 1: WhF16 frag-tile stores. Lane: e fixed (col), 4 consecutive m.
    int hb = h * 8 + b;
#pragma unroll
    for (int i = 0; i < 4; i++) {
        int mg = wr * 4 + i;
        int mt = (m_base >> 5) + (mg >> 1);
        int mhi = ((mg & 1) << 1) | (lq >> 1);
        int mlo = (lq & 1) * 4;
#pragma unroll
        for (int j = 0; j < 4; j++) {
            int e = e_base + (wc * 4 + j) * 16 + lr;
            int et = e >> 4, el = e & 15;
            ushort4 vs;
            vs.x = f2b(acc[i][j][0]);
            vs.y = f2b(acc[i][j][1]);
            vs.z = f2b(acc[i][j][2]);
            vs.w = f2b(acc[i][j][3]);
            size_t idx = ((size_t)(hb * 16 + et) * 32 + mt) * 512
                         + mhi * 128 + el * 8 + mlo;
            *(ushort4*)&WhF[idx] = vs;
        }
    }

    // Epilogue 2: f1/f2 partials via shfl-reduce over the 16-lane e-groups.
    const float LOG2E = 1.44269504f;
    float a1v[4], a2v[4];
#pragma unroll
    for (int j = 0; j < 4; j++) {
        int e = e_base + (wc * 4 + j) * 16 + lr;
        a1v[j] = b2f(a1b[h * 256 + e]);
        a2v[j] = b2f(a2b[h * 256 + e]);
    }
#pragma unroll
    for (int i = 0; i < 4; i++) {
#pragma unroll
        for (int reg = 0; reg < 4; reg++) {
            float s1 = 0.f, s2 = 0.f;
#pragma unroll
            for (int j = 0; j < 4; j++) {
                s1 += acc[i][j][reg] * a1v[j];
                s2 += acc[i][j][reg] * a2v[j];
            }
            s1 += __shfl_xor(s1, 1, 64); s2 += __shfl_xor(s2, 1, 64);
            s1 += __shfl_xor(s1, 2, 64); s2 += __shfl_xor(s2, 2, 64);
            s1 += __shfl_xor(s1, 4, 64); s2 += __shfl_xor(s2, 4, 64);
            s1 += __shfl_xor(s1, 8, 64); s2 += __shfl_xor(s2, 8, 64);
            if (lr == 0) {
                int m = m_base + (wr * 4 + i) * 16 + lq * 4 + reg;
                atomicAdd(&f1[hb * 1024 + m], s1 * LOG2E);
                atomicAdd(&f2[hb * 1024 + m], s2 * LOG2E);
            }
        }
    }
}

// K2K3 fused: masked-softmax attention + P@Wh + ELU + final GEMM + bias.
// Block = (b, 16 rows) x 4 waves; wave w runs head h=w's r10-proven k2 core
// (16 rows x 256 e x 1024 m, acc 64 AGPR, no spill, barrier-free K-loop).
// feat rows are then COMPLETE within the block: staged frag-ordered in 32KB
// LDS (one barrier), and the block computes out[16x64] = feat @ W_act + b
// directly (32 MFMAs/wave vs frag-tiled WactF). Eliminates the 33MB feat
// round-trip and the separate k3 launch. XCD swizzle: b = bid&7 -> per-XCD
// L2 set = 4 heads x 512KB = 2MB. f1/f2 pre-scaled by log2e -> native exp2.
__global__ __launch_bounds__(256, 2) void k2k3(
        const unsigned short* __restrict__ WhF,
        const unsigned int* __restrict__ maskT,     // [8][32][1024]
        const float* __restrict__ f1, const float* __restrict__ f2,
        const unsigned short* __restrict__ WactF,
        const unsigned short* __restrict__ bactb,
        void* __restrict__ out, const int* __restrict__ flag) {
    __shared__ unsigned short sfeat[32 * 512];      // 32KB, frag-ordered kt tiles
    int tid = threadIdx.x;
    int w = tid >> 6, lane = tid & 63;
    int lr = lane & 15, lq = lane >> 4;
    int b = blockIdx.x & 7;                         // XCD swizzle
    int n0 = (blockIdx.x >> 3) * 16;
    int h = w;
    int hb = h * 8 + b;
    int row = n0 + lr;                              // A-frag row = lr
    float f1n = f1[hb * 1024 + row];                // already *log2e
    const unsigned short* whb = WhF + (size_t)hb * 16 * 32 * 512 + lane * 8;
    const unsigned int* mrow = maskT + (size_t)b * 32 * 1024 + row;
    const float* f2row = f2 + hb * 1024;

    f32x4 acc[16] = {};                             // et tile: e = et*16 + lr
    float den = 0.f;

    for (int mt = 0; mt < 32; mt++) {
        int m0 = mt * 32;
        unsigned int mw = mrow[(size_t)mt * 1024];
        float4 fA = *(const float4*)(f2row + m0 + lq * 8);
        float4 fB = *(const float4*)(f2row + m0 + lq * 8 + 4);
        short8 fr1[8];
#pragma unroll
        for (int et = 0; et < 8; et++)
            fr1[et] = *(const short8*)(whb + (size_t)(et * 32 + mt) * 512);

        float fmv[8] = {fA.x, fA.y, fA.z, fA.w, fB.x, fB.y, fB.z, fB.w};
        unsigned int msh = mw >> (lq * 8);
        union { unsigned int u[4]; short8 v; } af;
#pragma unroll
        for (int pr = 0; pr < 4; pr++) {
            unsigned int ub[2];
#pragma unroll
            for (int q = 0; q < 2; q++) {
                int j = pr * 2 + q;
                float tL = f1n + fmv[j];               // log2-domain logit
                float eL = fmaxf(tL, 0.2f * tL);       // leaky relu
                float pv = ((msh >> j) & 1u) ? exp2f(eL) : 0.f;
                union { float f; unsigned int i; } pu; pu.f = pv;
                ub[q] = pu.i & 0xFFFF0000u;            // bf16 (truncate)
                union { unsigned int i; float f; } tb; tb.i = ub[q];
                den += tb.f;                           // consistent num/den
            }
            af.u[pr] = (ub[0] >> 16) | ub[1];
        }
        short8 fr2[8];
#pragma unroll
        for (int et = 0; et < 8; et++)
            fr2[et] = *(const short8*)(whb + (size_t)((et + 8) * 32 + mt) * 512);

#pragma unroll
        for (int et = 0; et < 8; et++)
            acc[et] = __builtin_amdgcn_mfma_f32_16x16x32_bf16(
                af.v, fr1[et], acc[et], 0, 0, 0);
#pragma unroll
        for (int et = 0; et < 8; et++)
            acc[8 + et] = __builtin_amdgcn_mfma_f32_16x16x32_bf16(
                af.v, fr2[et], acc[8 + et], 0, 0, 0);
    }

    // den: sum the 4 m-quads; then rdr per C-layout row
    den += __shfl_xor(den, 16, 64);
    den += __shfl_xor(den, 32, 64);
    float rdr[4];
#pragma unroll
    for (int reg = 0; reg < 4; reg++)
        rdr[reg] = 1.0f / __shfl(den, lq * 4 + reg, 64);

    // softmax+elu -> frag-ordered LDS stage. Wave w owns kt = w*8..w*8+7.
#pragma unroll
    for (int et = 0; et < 16; et++) {
        int kt = h * 8 + (et >> 1);
        int sub = (et & 1) * 2 + (lr >> 3);
        int j = lr & 7;
#pragma unroll
        for (int reg = 0; reg < 4; reg++) {
            int r = lq * 4 + reg;
            float v = acc[et][reg] * rdr[reg];
            float o = v > 0.f ? v : __expf(v) - 1.f;   // elu
            sfeat[kt * 512 + (sub * 16 + r) * 8 + j] = f2b(o);
        }
    }
    __syncthreads();

    // k3: wave w computes out cols w*16..w*16+15 for the block's 16 rows.
    f32x4 oacc = {};
#pragma unroll 8
    for (int kt = 0; kt < 32; kt++) {
        short8 a = *(const short8*)&sfeat[kt * 512 + lane * 8];
        short8 bf = *(const short8*)&WactF[(size_t)(kt * 4 + w) * 512 + lane * 8];
        oacc = __builtin_amdgcn_mfma_f32_16x16x32_bf16(a, bf, oacc, 0, 0, 0);
    }
    int bf16out = *flag;
    int col = w * 16 + lr;
    float bv = b2f(bactb[col]);
#pragma unroll
    for (int reg = 0; reg < 4; reg++) {
        int r = b * 1024 + n0 + lq * 4 + reg;
        float val = oacc[reg] + bv;
        if (bf16out) ((unsigned short*)out)[(size_t)r * 64 + col] = f2b(val);
        else         ((float*)out)[(size_t)r * 64 + col] = val;
    }
}

extern "C" void kernel_launch(void* const* d_in, const int* in_sizes, int n_in,
                              void* d_out, int out_size, void* d_ws, size_t ws_size,
                              hipStream_t stream) {
    const void* x    = d_in[0];
    const int*  adj  = (const int*)d_in[1];
    const void* W    = d_in[2];
    const void* a1   = d_in[3];
    const void* a2   = d_in[4];
    const void* Wact = d_in[5];
    const void* bact = d_in[6];

    char* ws = (char*)d_ws;
    unsigned short* WhF   = (unsigned short*)(ws);               // 16 MB  frag-tile
    unsigned short* xb    = (unsigned short*)(ws + 16777216);    // 16 MB
    unsigned short* WT    = (unsigned short*)(ws + 33554432);    //  2 MB  [4][256][1024]
    unsigned int*   maskT = (unsigned int*)(ws + 33554432);      //  1 MB  (== WT, after k1)
    unsigned short* WactF = (unsigned short*)(ws + 35651584);    // 128 KB frag-tile
    float*          f1    = (float*)(ws + 35782656);             // 128 KB [32][1024]
    float*          f2    = (float*)(ws + 35913728);             // 128 KB [32][1024]
    unsigned short* a1b   = (unsigned short*)(ws + 36044800);    // 2 KB
    unsigned short* a2b   = (unsigned short*)(ws + 36046848);    // 2 KB
    unsigned short* bactb = (unsigned short*)(ws + 36048896);    // 128 B
    int*            flag  = (int*)(ws + 36049024);               // 16 B
    if (ws_size < (size_t)36049040) return;

    prep_all<<<4433, 256, 0, stream>>>((const unsigned int*)x, x, W, Wact,
                                       a1, a2, bact, xb, WT, WactF,
                                       a1b, a2b, bactb, flag, (float4*)f1);
    k1_gemm<<<dim3(8, 64), 256, 0, stream>>>(xb, WT, WhF, a1b, a2b, f1, f2);
    pack_adj<<<32768, 256, 0, stream>>>(adj, maskT);   // overwrites WT (dead)
    k2k3<<<512, 256, 0, stream>>>(WhF, maskT, f1, f2, WactF, bactb, d_out, flag);
}

// Round 12
// 222.141 us; speedup vs baseline: 1.3717x; 1.3717x over previous
//
#include <hip/hip_runtime.h>
#include <stdint.h>

// Problem constants: B=8, N=1024, IN_F=1024, E=256, H=4, A=64
typedef __attribute__((ext_vector_type(8))) short short8;
typedef __attribute__((ext_vector_type(4))) float f32x4;
typedef __attribute__((ext_vector_type(16))) float f32x16;

// WhF frag-tile layout (32x32 MFMA-B order; k1 epilogue -> k2):
//   element (hb, e, m): et=e>>5, e31=e&31, m16=m>>4, l5=(m>>3)&1, m7=m&7
//   u16 idx = ((hb*8+et)*64 + m16)*512 + (l5*32+e31)*8 + m7
// => one (et,m16) tile is 1KB contiguous in lane order (lane=l5*32+e31).

__device__ __forceinline__ float b2f(unsigned short u) {
    union { unsigned int i; float f; } v; v.i = ((unsigned int)u) << 16; return v.f;
}
__device__ __forceinline__ unsigned short f2b(float f) {
    union { float f; unsigned int i; } v; v.f = f;
    unsigned int u = v.i;
    u = (u + 0x7FFFu + ((u >> 16) & 1u)) >> 16;
    return (unsigned short)u;
}
__device__ __forceinline__ void glds16(const void* g, const void* l) {
    __builtin_amdgcn_global_load_lds(
        (const __attribute__((address_space(1))) unsigned int*)g,
        (__attribute__((address_space(3))) unsigned int*)l, 16, 0, 0);
}

__device__ __forceinline__ void cvt8(const void* in, unsigned short* out,
                                     int f, int grp) {
    if (f) {
        ((ushort4*)out)[grp * 2]     = ((const ushort4*)in)[grp * 2];
        ((ushort4*)out)[grp * 2 + 1] = ((const ushort4*)in)[grp * 2 + 1];
    } else {
        const float4* p = (const float4*)in + (size_t)grp * 2;
        float4 a = p[0], b = p[1];
        ushort4 o0, o1;
        o0.x = f2b(a.x); o0.y = f2b(a.y); o0.z = f2b(a.z); o0.w = f2b(a.w);
        o1.x = f2b(b.x); o1.y = f2b(b.y); o1.z = f2b(b.z); o1.w = f2b(b.w);
        ((ushort4*)out)[grp * 2]     = o0;
        ((ushort4*)out)[grp * 2 + 1] = o1;
    }
}

// prep_all: single launch replacing prep+conv8+t2+zero.
// Blocks: [0,4096) x-convert | [4096,4352) W transpose | [4352,4416) zero f1/f2
//         | 4416 smalls+flag | [4417,4433) W_act transpose (1024x64 -> 64x1024).
// Each block re-derives the dtype flag from x[0:64] (256B, L2-hot).
__global__ __launch_bounds__(256) void prep_all(
        const unsigned int* __restrict__ x4,
        const void* __restrict__ x, const void* __restrict__ W,
        const void* __restrict__ Wact,
        const void* __restrict__ a1, const void* __restrict__ a2,
        const void* __restrict__ bact,
        unsigned short* __restrict__ xb, unsigned short* __restrict__ WT,
        unsigned short* __restrict__ WactT,
        unsigned short* __restrict__ a1b, unsigned short* __restrict__ a2b,
        unsigned short* __restrict__ bactb,
        int* __restrict__ flag, float4* __restrict__ fz) {
    __shared__ unsigned int tile[64 * 65];
    __shared__ int sflag;
    int tid = threadIdx.x;
    int bid = blockIdx.x;
    if (bid >= 4352 && bid < 4416) {                  // zero f1/f2 (256 KB)
        fz[(bid - 4352) * 256 + tid] = float4{0.f, 0.f, 0.f, 0.f};
        return;
    }
    if (tid < 64) {                                   // per-block dtype detect
        unsigned int wv = x4[tid];
        unsigned int e = (wv >> 7) & 0xFF;
        unsigned long long m = __ballot(e >= 100 && e <= 140);
        if (tid == 0) sflag = (__popcll(m) >= 48) ? 1 : 0;
    }
    __syncthreads();
    int f = sflag;

    if (bid < 4096) {                                 // x -> xb bf16
        cvt8(x, xb, f, bid * 256 + tid);
        return;
    }
    if (bid == 4416) {                                // smalls + flag publish
        if (tid == 0) flag[0] = f;
        if (tid < 128) cvt8(a1, a1b, f, tid);
        else           cvt8(a2, a2b, f, tid - 128);
        if (tid < 8)   cvt8(bact, bactb, f, tid);
        return;
    }
    // LDS-tiled transpose: W (256 blocks, C=256) or W_act (16 blocks, C=64).
    const void* in; unsigned short* out; int C, bt, c0, r0;
    if (bid < 4352) {
        int lb = bid - 4096;
        in = W; out = WT; C = 256;
        c0 = (lb & 3) * 64;
        r0 = ((lb >> 2) & 15) * 64;
        bt = lb >> 6;
    } else {
        int lb = bid - 4417;
        in = Wact; out = WactT; C = 64;
        c0 = 0; r0 = lb * 64; bt = 0;
    }
    int rl = tid >> 2;
    int cc = (tid & 3) * 16;
    size_t ibase = ((size_t)bt * 1024 + (r0 + rl)) * C + c0 + cc;
    unsigned short v[16];
    if (f) {
        const unsigned short* p = (const unsigned short*)in + ibase;
        short8 a = *(const short8*)p;
        short8 b = *(const short8*)(p + 8);
#pragma unroll
        for (int j = 0; j < 8; j++) { v[j] = (unsigned short)a[j]; v[8 + j] = (unsigned short)b[j]; }
    } else {
        const float* p = (const float*)in + ibase;
#pragma unroll
        for (int j = 0; j < 16; j++) v[j] = f2b(p[j]);
    }
#pragma unroll
    for (int j = 0; j < 16; j++)
        tile[(cc + j) * 65 + rl] = v[j];
    __syncthreads();
    int cl = tid >> 2;
    int rch = (tid & 3) * 16;
    unsigned short o[16];
#pragma unroll
    for (int j = 0; j < 16; j++)
        o[j] = (unsigned short)tile[cl * 65 + rch + j];
    unsigned short* op = out + ((size_t)bt * C + (c0 + cl)) * 1024 + r0 + rch;
#pragma unroll
    for (int q = 0; q < 4; q++) {
        ushort4 s; s.x = o[q*4]; s.y = o[q*4+1]; s.z = o[q*4+2]; s.w = o[q*4+3];
        ((ushort4*)op)[q] = s;
    }
}

// Pack adj into TRANSPOSED bitmask maskT[b][mword=m>>5][n] (u32), via ballot.
__global__ void pack_adj(const int* __restrict__ adj,
                         unsigned int* __restrict__ maskT) {
    int gid = blockIdx.x * 256 + threadIdx.x;
    int lane = threadIdx.x & 63;
    unsigned long long m = __ballot(adj[gid] > 0);
    if (lane == 0) {
        int lin = gid >> 6;           // (b*1024+n)*16 + m0/64
        int mw = (lin & 15) * 2;
        int bn = lin >> 4;
        int b = bn >> 10, n = bn & 1023;
        maskT[(size_t)(b * 32 + mw) * 1024 + n]     = (unsigned int)m;
        maskT[(size_t)(b * 32 + mw + 1) * 1024 + n] = (unsigned int)(m >> 32);
    }
}

// K1: Wh = x @ W[h] -> WhF frag-tile bf16 (32x32 layout). Epilogue also
// accumulates f1 = Wh.a1, f2 = Wh.a2 (pre-scaled by log2e) via shfl+atomics.
__global__ __launch_bounds__(256) void k1_gemm(
        const unsigned short* __restrict__ x,
        const unsigned short* __restrict__ WT,      // [H][E=256][K=1024]
        unsigned short* __restrict__ WhF,
        const unsigned short* __restrict__ a1b,
        const unsigned short* __restrict__ a2b,
        float* __restrict__ f1, float* __restrict__ f2) {
    __shared__ unsigned short smA[8 * 512];
    __shared__ unsigned short smB[8 * 512];
    int tid = threadIdx.x;
    int w = tid >> 6, lane = tid & 63;
    int lr = lane & 15, lq = lane >> 4;
    int col0 = blockIdx.x * 128;
    int row0 = blockIdx.y * 128;
    int h = col0 >> 8;
    int e_base = col0 & 255;
    int b = row0 >> 10;
    int m_base = row0 & 1023;
    int wr = w >> 1, wc = w & 1;

    f32x4 acc[4][4] = {};

    for (int k0 = 0; k0 < 1024; k0 += 32) {
        __syncthreads();
#pragma unroll
        for (int s = 0; s < 2; s++) {
            int g = 2 * w + s;
            const unsigned short* srcA =
                x + (size_t)(row0 + g * 16 + lr) * 1024 + k0 + lq * 8;
            glds16(srcA, &smA[g * 512]);
            const unsigned short* srcB =
                WT + (size_t)(h * 256 + e_base + g * 16 + lr) * 1024 + k0 + lq * 8;
            glds16(srcB, &smB[g * 512]);
        }
        __syncthreads();
        short8 af[4], bf[4];
#pragma unroll
        for (int i = 0; i < 4; i++)
            af[i] = *(const short8*)&smA[(wr * 4 + i) * 512 + lane * 8];
#pragma unroll
        for (int j = 0; j < 4; j++)
            bf[j] = *(const short8*)&smB[(wc * 4 + j) * 512 + lane * 8];
#pragma unroll
        for (int i = 0; i < 4; i++)
#pragma unroll
            for (int j = 0; j < 4; j++)
                acc[i][j] = __builtin_amdgcn_mfma_f32_16x16x32_bf16(
                    af[i], bf[j], acc[i][j], 0, 0, 0);
    }

    // Epilogue 1: WhF frag-tile stores (32x32 layout).
    int hb = h * 8 + b;
#pragma unroll
    for (int i = 0; i < 4; i++) {
#pragma unroll
        for (int j = 0; j < 4; j++) {
            int e = e_base + (wc * 4 + j) * 16 + lr;
            int et = e >> 5, e31 = e & 31;
            int m16 = (m_base >> 4) + wr * 4 + i;
            ushort4 vs;
            vs.x = f2b(acc[i][j][0]);
            vs.y = f2b(acc[i][j][1]);
            vs.z = f2b(acc[i][j][2]);
            vs.w = f2b(acc[i][j][3]);
            size_t idx = ((size_t)((hb * 8 + et) * 64 + m16) * 512)
                         + ((lq >> 1) * 32 + e31) * 8 + (lq & 1) * 4;
            *(ushort4*)&WhF[idx] = vs;
        }
    }

    // Epilogue 2: f1/f2 partials via shfl-reduce over the 16-lane e-groups.
    const float LOG2E = 1.44269504f;
    float a1v[4], a2v[4];
#pragma unroll
    for (int j = 0; j < 4; j++) {
        int e = e_base + (wc * 4 + j) * 16 + lr;
        a1v[j] = b2f(a1b[h * 256 + e]);
        a2v[j] = b2f(a2b[h * 256 + e]);
    }
#pragma unroll
    for (int i = 0; i < 4; i++) {
#pragma unroll
        for (int reg = 0; reg < 4; reg++) {
            float s1 = 0.f, s2 = 0.f;
#pragma unroll
            for (int j = 0; j < 4; j++) {
                s1 += acc[i][j][reg] * a1v[j];
                s2 += acc[i][j][reg] * a2v[j];
            }
            s1 += __shfl_xor(s1, 1, 64); s2 += __shfl_xor(s2, 1, 64);
            s1 += __shfl_xor(s1, 2, 64); s2 += __shfl_xor(s2, 2, 64);
            s1 += __shfl_xor(s1, 4, 64); s2 += __shfl_xor(s2, 4, 64);
            s1 += __shfl_xor(s1, 8, 64); s2 += __shfl_xor(s2, 8, 64);
            if (lr == 0) {
                int m = m_base + (wr * 4 + i) * 16 + lq * 4 + reg;
                atomicAdd(&f1[hb * 1024 + m], s1 * LOG2E);
                atomicAdd(&f2[hb * 1024 + m], s2 * LOG2E);
            }
        }
    }
}

// K2: masked-softmax attention + P@Wh + ELU -> feat[bn][h*256+e] bf16.
// PROVEN-BEST core (round-5 submission, measured 53.3us, VGPR 100, no spill):
// barrier-free, no LDS. Wave = 32 rows x 128 e (e-half), 32x32x16 MFMA,
// B-frags are contiguous 1KB tiles (lane*16B, fully coalesced, L2-resident
// via XCD swizzle). Register double-buffer prefetches iter+1's frags.
// Only change vs r5: __expf -> exp2f (f1/f2 pre-scaled by log2e in k1;
// leakyrelu commutes with the positive scale).
__global__ __launch_bounds__(256, 2) void k2_attn(
        const unsigned short* __restrict__ WhF,
        const unsigned int* __restrict__ maskT,     // [8][32][1024]
        const float* __restrict__ f1, const float* __restrict__ f2,
        unsigned short* __restrict__ feat) {
    int tid = threadIdx.x;
    int w = tid >> 6, lane = tid & 63;
    int l5 = lane >> 5, l31 = lane & 31;
    int bid = blockIdx.x;
    int xcd = bid & 7, idx = bid >> 3;          // idx 0..63
    int hb = xcd + 8 * (idx >> 4);
    int sub = idx & 15;
    int wid = sub * 4 + w;                      // 0..63 within hb
    int rg = wid >> 1;                          // row-group 0..31
    int ehalf = wid & 1;
    int n0 = rg * 32;
    int h = hb >> 3, b = hb & 7;
    int row = n0 + l31;
    float f1n = f1[hb * 1024 + row];            // already *log2e
    const unsigned short* whb = WhF + (size_t)(hb * 8 + ehalf * 4) * 64 * 512
                                + lane * 8;
    const unsigned int* mrow = maskT + (size_t)b * 32 * 1024 + row;
    const float* f2row = f2 + hb * 1024;

    f32x16 acc[4] = {};                         // e = ehalf*128 + et*32 + l31
    float den = 0.f;

    short8 buf[2][4][2];
#pragma unroll
    for (int et = 0; et < 4; et++)
#pragma unroll
        for (int ks = 0; ks < 2; ks++)
            buf[0][et][ks] = *(const short8*)(whb + (size_t)(et * 64 + ks) * 512);

#pragma unroll 2
    for (int m0 = 0; m0 < 1024; m0 += 32) {
        int p = (m0 >> 5) & 1;
        // prefetch next iteration's B-frags (coalesced 1KB per instr)
        if (m0 + 32 < 1024) {
            int m16n = (m0 >> 4) + 2;
#pragma unroll
            for (int et = 0; et < 4; et++)
#pragma unroll
                for (int ks = 0; ks < 2; ks++)
                    buf[p ^ 1][et][ks] =
                        *(const short8*)(whb + (size_t)(et * 64 + m16n + ks) * 512);
        }
        unsigned int mw = mrow[(size_t)(m0 >> 5) * 1024];
        float4 fA0 = *(const float4*)(f2row + m0 + l5 * 8);
        float4 fA1 = *(const float4*)(f2row + m0 + l5 * 8 + 4);
        float4 fB0 = *(const float4*)(f2row + m0 + 16 + l5 * 8);
        float4 fB1 = *(const float4*)(f2row + m0 + 16 + l5 * 8 + 4);
        float fm[16] = {fA0.x,fA0.y,fA0.z,fA0.w, fA1.x,fA1.y,fA1.z,fA1.w,
                        fB0.x,fB0.y,fB0.z,fB0.w, fB1.x,fB1.y,fB1.z,fB1.w};
        short8 af[2];
#pragma unroll
        for (int ks = 0; ks < 2; ks++) {
#pragma unroll
            for (int j = 0; j < 8; j++) {
                float t_ = f1n + fm[ks * 8 + j];
                float e_ = fmaxf(t_, 0.2f * t_);                   // leaky relu
                float pv = ((mw >> (ks * 16 + l5 * 8 + j)) & 1u) ? exp2f(e_) : 0.f;
                unsigned short pb = f2b(pv);
                af[ks][j] = (short)pb;
                den += b2f(pb);      // bf16-rounded p: consistent num/denom
            }
        }
#pragma unroll
        for (int et = 0; et < 4; et++)
#pragma unroll
            for (int ks = 0; ks < 2; ks++)
                acc[et] = __builtin_amdgcn_mfma_f32_32x32x16_bf16(
                    af[ks], buf[p][et][ks], acc[et], 0, 0, 0);
    }

    // den: lane holds partial for row l31 over its k-half; combine halves
    den += __shfl_xor(den, 32, 64);

#pragma unroll
    for (int reg = 0; reg < 16; reg++) {
        int r = (reg & 3) + 8 * (reg >> 2) + 4 * l5;   // C-layout row (0..31)
        float dr = __shfl(den, r, 64);
        float rdr = 1.0f / dr;
        int nn = n0 + r;
#pragma unroll
        for (int et = 0; et < 4; et++) {
            int e = ehalf * 128 + et * 32 + l31;
            float v = acc[et][reg] * rdr;
            float o = v > 0.f ? v : __expf(v) - 1.f;   // elu
            feat[(size_t)(b * 1024 + nn) * 1024 + h * 256 + e] = f2b(o);
        }
    }
}

// K3: out = feat @ W_act + b_act  (M=8192, K=1024, N=64), out dtype per flag.
__global__ __launch_bounds__(256) void k3_out(
        const unsigned short* __restrict__ feat,
        const unsigned short* __restrict__ WactT,   // [64][1024]
        const unsigned short* __restrict__ bact,
        void* __restrict__ out, const int* __restrict__ flag) {
    __shared__ unsigned short smA[2 * 512];
    __shared__ unsigned short smB[4 * 512];
    int tid = threadIdx.x;
    int w = tid >> 6, lane = tid & 63;
    int lr = lane & 15, lq = lane >> 4;
    int row0 = blockIdx.x * 32;
    int g = w & 1, ch = w >> 1;
    int bf16out = *flag;
    f32x4 acc[2] = {};

    for (int k0 = 0; k0 < 1024; k0 += 32) {
        __syncthreads();
        if (w < 2) {
            const unsigned short* src =
                feat + (size_t)(row0 + w * 16 + lr) * 1024 + k0 + lq * 8;
            glds16(src, &smA[w * 512]);
        } else {
#pragma unroll
            for (int s = 0; s < 2; s++) {
                int t = (w - 2) * 2 + s;
                const unsigned short* src =
                    WactT + (size_t)(t * 16 + lr) * 1024 + k0 + lq * 8;
                glds16(src, &smB[t * 512]);
            }
        }
        __syncthreads();
        short8 af = *(const short8*)&smA[g * 512 + lane * 8];
#pragma unroll
        for (int j = 0; j < 2; j++) {
            short8 bf = *(const short8*)&smB[(ch * 2 + j) * 512 + lane * 8];
            acc[j] = __builtin_amdgcn_mfma_f32_16x16x32_bf16(af, bf, acc[j], 0, 0, 0);
        }
    }
#pragma unroll
    for (int j = 0; j < 2; j++) {
        int col = ch * 32 + j * 16 + lr;
        float bv = b2f(bact[col]);
#pragma unroll
        for (int rr = 0; rr < 4; rr++) {
            int r = row0 + g * 16 + lq * 4 + rr;
            float val = acc[j][rr] + bv;
            if (bf16out) ((unsigned short*)out)[(size_t)r * 64 + col] = f2b(val);
            else         ((float*)out)[(size_t)r * 64 + col] = val;
        }
    }
}

extern "C" void kernel_launch(void* const* d_in, const int* in_sizes, int n_in,
                              void* d_out, int out_size, void* d_ws, size_t ws_size,
                              hipStream_t stream) {
    const void* x    = d_in[0];
    const int*  adj  = (const int*)d_in[1];
    const void* W    = d_in[2];
    const void* a1   = d_in[3];
    const void* a2   = d_in[4];
    const void* Wact = d_in[5];
    const void* bact = d_in[6];

    char* ws = (char*)d_ws;
    unsigned short* WhF   = (unsigned short*)(ws);               // 16 MB  frag-tile
    unsigned short* xb    = (unsigned short*)(ws + 16777216);    // 16 MB  (== feat)
    unsigned short* feat  = (unsigned short*)(ws + 16777216);    // 16 MB  [8192][1024]
    unsigned short* WT    = (unsigned short*)(ws + 33554432);    //  2 MB  [4][256][1024]
    unsigned int*   maskT = (unsigned int*)(ws + 33554432);      //  1 MB  (== WT, after k1)
    unsigned short* WactT = (unsigned short*)(ws + 35651584);    // 128 KB [64][1024]
    float*          f1    = (float*)(ws + 35782656);             // 128 KB [32][1024]
    float*          f2    = (float*)(ws + 35913728);             // 128 KB [32][1024]
    unsigned short* a1b   = (unsigned short*)(ws + 36044800);    // 2 KB
    unsigned short* a2b   = (unsigned short*)(ws + 36046848);    // 2 KB
    unsigned short* bactb = (unsigned short*)(ws + 36048896);    // 128 B
    int*            flag  = (int*)(ws + 36049024);               // 16 B
    if (ws_size < (size_t)36049040) return;

    prep_all<<<4433, 256, 0, stream>>>((const unsigned int*)x, x, W, Wact,
                                       a1, a2, bact, xb, WT, WactT,
                                       a1b, a2b, bactb, flag, (float4*)f1);
    k1_gemm<<<dim3(8, 64), 256, 0, stream>>>(xb, WT, WhF, a1b, a2b, f1, f2);
    pack_adj<<<32768, 256, 0, stream>>>(adj, maskT);   // overwrites WT (dead)
    k2_attn<<<512, 256, 0, stream>>>(WhF, maskT, f1, f2, feat);
    k3_out<<<256, 256, 0, stream>>>(feat, WactT, bactb, d_out, flag);
}